// Round 1
// baseline (964.562 us; speedup 1.0000x reference)
//
#include <hip/hip_runtime.h>
#include <math.h>

// MMD loss: N=M=4096, D=1024, sigma^2 = 2025.
// mmd = (S_xx - n)/(n(n-1)) + (S_yy - m)/(m(m-1)) - 2*S_xy/(n*m)
// where S_ab = sum_{i,j} exp(-(||a_i||^2 + ||b_j||^2 - 2 a_i.b_j)/sigma^2).
// S_xx, S_yy symmetric -> triangular tiles with weight 2 off-diagonal.
// Per-term math in fp32 (random errors average out; __expf bias cancels
// across the xx+yy-2xy combination); cross-block accumulation in fp64
// (required: S ~ 6.1e6 with ~0.4 absolute budget after cancellation).

#define NROWS 4096
#define MROWS 4096
#define DDIM  1024
#define BM    128
#define BK    16
#define NT    (NROWS / BM)           // 32 tiles per dim
#define TRI   (NT * (NT + 1) / 2)    // 528 triangular tiles
#define NBLK  (2 * TRI + NT * NT)    // 528 + 528 + 1024 = 2080 blocks
#define LDPAD (BM + 4)               // 132: breaks power-of-2 bank stride

__global__ __launch_bounds__(256) void norms_kernel(const float* __restrict__ X,
                                                    const float* __restrict__ Y,
                                                    float* __restrict__ nx,
                                                    float* __restrict__ ny) {
    int row = blockIdx.x;
    const float* src = (row < NROWS) ? (X + (size_t)row * DDIM)
                                     : (Y + (size_t)(row - NROWS) * DDIM);
    int t = threadIdx.x;
    // 1024 floats / 256 threads = one float4 per thread
    float4 v = ((const float4*)src)[t];
    float s = v.x * v.x + v.y * v.y + v.z * v.z + v.w * v.w;
    __shared__ float red[256];
    red[t] = s;
    __syncthreads();
    for (int off = 128; off > 0; off >>= 1) {
        if (t < off) red[t] += red[t + off];
        __syncthreads();
    }
    if (t == 0) {
        if (row < NROWS) nx[row] = red[0];
        else             ny[row - NROWS] = red[0];
    }
}

__global__ __launch_bounds__(256) void mmd_tiles(const float* __restrict__ X,
                                                 const float* __restrict__ Y,
                                                 const float* __restrict__ nx,
                                                 const float* __restrict__ ny,
                                                 double* __restrict__ partials) {
    __shared__ float As[BK][LDPAD];
    __shared__ float Bs[BK][LDPAD];
    __shared__ double red[256];

    const int b = blockIdx.x;
    const float *A, *B, *nA, *nB;
    int tr, tc;
    double coef;
    if (b < 2 * TRI) {
        // triangular decode: tiles (r,c) with c >= r
        int u = (b < TRI) ? b : b - TRI;
        int r = 0;
        while (u >= NT - r) { u -= NT - r; r++; }
        tr = r; tc = r + u;
        double w = (tr == tc) ? 1.0 : 2.0;  // off-diagonal tiles count twice
        if (b < TRI) { A = X; B = X; nA = nx; nB = nx;
                       coef = w / ((double)NROWS * (double)(NROWS - 1)); }
        else         { A = Y; B = Y; nA = ny; nB = ny;
                       coef = w / ((double)MROWS * (double)(MROWS - 1)); }
    } else {
        int u = b - 2 * TRI;
        tr = u / NT; tc = u % NT;
        A = X; B = Y; nA = nx; nB = ny;
        coef = -2.0 / ((double)NROWS * (double)MROWS);
    }

    const int t  = threadIdx.x;
    const int tx = t & 15;   // 16 thread-cols
    const int ty = t >> 4;   // 16 thread-rows

    const float* Ab = A + (size_t)tr * BM * DDIM;
    const float* Bb = B + (size_t)tc * BM * DDIM;

    // staging: 128 rows x 4 float4-chunks = 512 slots; 2 slots/thread
    const int lr = t >> 2;   // 0..63
    const int lc = t & 3;    // 0..3
    const float* Aptr0 = Ab + (size_t)lr * DDIM + lc * 4;
    const float* Aptr1 = Ab + (size_t)(lr + 64) * DDIM + lc * 4;
    const float* Bptr0 = Bb + (size_t)lr * DDIM + lc * 4;
    const float* Bptr1 = Bb + (size_t)(lr + 64) * DDIM + lc * 4;

    float acc[8][8];
    #pragma unroll
    for (int i = 0; i < 8; i++)
        #pragma unroll
        for (int j = 0; j < 8; j++) acc[i][j] = 0.f;

    // prefetch chunk 0
    float4 a0 = *(const float4*)(Aptr0);
    float4 a1 = *(const float4*)(Aptr1);
    float4 b0 = *(const float4*)(Bptr0);
    float4 b1 = *(const float4*)(Bptr1);

    for (int k0 = 0; k0 < DDIM; k0 += BK) {
        __syncthreads();
        const int kk = lc * 4;
        // transposed store As[k][row]; LDPAD=132 -> worst 2-way conflict (free)
        As[kk + 0][lr] = a0.x; As[kk + 1][lr] = a0.y;
        As[kk + 2][lr] = a0.z; As[kk + 3][lr] = a0.w;
        As[kk + 0][lr + 64] = a1.x; As[kk + 1][lr + 64] = a1.y;
        As[kk + 2][lr + 64] = a1.z; As[kk + 3][lr + 64] = a1.w;
        Bs[kk + 0][lr] = b0.x; Bs[kk + 1][lr] = b0.y;
        Bs[kk + 2][lr] = b0.z; Bs[kk + 3][lr] = b0.w;
        Bs[kk + 0][lr + 64] = b1.x; Bs[kk + 1][lr + 64] = b1.y;
        Bs[kk + 2][lr + 64] = b1.z; Bs[kk + 3][lr + 64] = b1.w;
        __syncthreads();

        // prefetch next chunk: issued before compute so ~2000 VALU cycles
        // hide the global (L2-resident) latency
        if (k0 + BK < DDIM) {
            a0 = *(const float4*)(Aptr0 + k0 + BK);
            a1 = *(const float4*)(Aptr1 + k0 + BK);
            b0 = *(const float4*)(Bptr0 + k0 + BK);
            b1 = *(const float4*)(Bptr1 + k0 + BK);
        }

        #pragma unroll
        for (int k = 0; k < BK; k++) {
            float4 av0 = *(const float4*)&As[k][ty * 4];
            float4 av1 = *(const float4*)&As[k][ty * 4 + 64];
            float4 bv0 = *(const float4*)&Bs[k][tx * 4];
            float4 bv1 = *(const float4*)&Bs[k][tx * 4 + 64];
            float av[8] = {av0.x, av0.y, av0.z, av0.w, av1.x, av1.y, av1.z, av1.w};
            float bv[8] = {bv0.x, bv0.y, bv0.z, bv0.w, bv1.x, bv1.y, bv1.z, bv1.w};
            #pragma unroll
            for (int i = 0; i < 8; i++)
                #pragma unroll
                for (int j = 0; j < 8; j++)
                    acc[i][j] = fmaf(av[i], bv[j], acc[i][j]);
        }
    }

    // epilogue: d^2 = na + nb - 2*dot;  term = exp(-d^2/2025)
    float na[8], nb[8];
    #pragma unroll
    for (int i = 0; i < 4; i++) {
        na[i]     = nA[tr * BM + ty * 4 + i];
        na[i + 4] = nA[tr * BM + 64 + ty * 4 + i];
        nb[i]     = nB[tc * BM + tx * 4 + i];
        nb[i + 4] = nB[tc * BM + 64 + tx * 4 + i];
    }
    const float inv_s2 = 1.0f / 2025.0f;
    float lsum = 0.f;
    #pragma unroll
    for (int i = 0; i < 8; i++)
        #pragma unroll
        for (int j = 0; j < 8; j++) {
            float arg = (2.f * acc[i][j] - na[i] - nb[j]) * inv_s2;
            lsum += __expf(arg);
        }

    // block reduction in fp64
    red[t] = (double)lsum;
    __syncthreads();
    for (int off = 128; off > 0; off >>= 1) {
        if (t < off) red[t] += red[t + off];
        __syncthreads();
    }
    if (t == 0) partials[b] = red[0] * coef;
}

__global__ __launch_bounds__(256) void final_reduce(const double* __restrict__ partials,
                                                    float* __restrict__ out) {
    __shared__ double red[256];
    int t = threadIdx.x;
    double s = 0.0;
    for (int i = t; i < NBLK; i += 256) s += partials[i];
    red[t] = s;
    __syncthreads();
    for (int off = 128; off > 0; off >>= 1) {
        if (t < off) red[t] += red[t + off];
        __syncthreads();
    }
    if (t == 0) {
        // analytic diagonal subtraction: n/(n(n-1)) = 1/(n-1), same for m
        double mmd = red[0] - 1.0 / (double)(NROWS - 1) - 1.0 / (double)(MROWS - 1);
        out[0] = (float)mmd;
    }
}

extern "C" void kernel_launch(void* const* d_in, const int* in_sizes, int n_in,
                              void* d_out, int out_size, void* d_ws, size_t ws_size,
                              hipStream_t stream) {
    const float* X = (const float*)d_in[0];   // inputs  [4096,1024] fp32
    const float* Y = (const float*)d_in[1];   // samples [4096,1024] fp32
    float* out = (float*)d_out;               // scalar fp32

    // workspace layout: [NBLK doubles partials][4096 fl nx][4096 fl ny]
    double* partials = (double*)d_ws;
    float* nx = (float*)((char*)d_ws + (size_t)NBLK * sizeof(double));
    float* ny = nx + NROWS;

    norms_kernel<<<NROWS + MROWS, 256, 0, stream>>>(X, Y, nx, ny);
    mmd_tiles<<<NBLK, 256, 0, stream>>>(X, Y, nx, ny, partials);
    final_reduce<<<1, 256, 0, stream>>>(partials, out);
}

// Round 2
// 308.082 us; speedup vs baseline: 3.1309x; 3.1309x over previous
//
#include <hip/hip_runtime.h>
#include <math.h>

// MMD loss via split-precision bf16 MFMA. N=M=4096, D=1024, sigma^2=2025.
// dot(x,y) ~= hi_x.hi_y + hi_x.lo_y + lo_x.hi_y  (3 bf16 MFMAs, fp32 acc)
// where hi=bf16(x), lo=bf16(x-hi) -> ~16-bit effective mantissa; omitted
// lo.lo term is ~2^-18 relative, random-sign -> averages out over 16.7M terms.
// Norms in fp32, cross-block accumulation in fp64 (S ~ 6.1e6, budget ~0.4).
// Diagonal of k_xx/k_yy subtracted analytically (exp(diag)=1 to ~3e-7).

typedef __bf16 bf16_t;
typedef __bf16 bf16x4 __attribute__((ext_vector_type(4)));
typedef __bf16 bf16x8 __attribute__((ext_vector_type(8)));
typedef float floatx4 __attribute__((ext_vector_type(4)));

#define NROWS 4096
#define MROWS 4096
#define DDIM  1024
#define BM    128
#define BK    32                      // bf16 elements per K-step (64 B/row)
#define NT    (NROWS / BM)            // 32 tiles per dim
#define TRI   (NT * (NT + 1) / 2)     // 528 triangular tiles
#define NBLK  (2 * TRI + NT * NT)     // 2080 blocks

// ---------------------------------------------------------------- convert
// One block per row (X rows then Y rows): fp32 -> (hi, lo) bf16 + fp32 norm.
__global__ __launch_bounds__(256) void convert_kernel(
    const float* __restrict__ X, const float* __restrict__ Y,
    bf16_t* __restrict__ Xhi, bf16_t* __restrict__ Xlo,
    bf16_t* __restrict__ Yhi, bf16_t* __restrict__ Ylo,
    float* __restrict__ nx, float* __restrict__ ny) {
    int row = blockIdx.x;
    const float* src;
    bf16_t *hi, *lo;
    float* nrm;
    int r;
    if (row < NROWS) {
        src = X + (size_t)row * DDIM;
        hi = Xhi + (size_t)row * DDIM; lo = Xlo + (size_t)row * DDIM;
        nrm = nx; r = row;
    } else {
        r = row - NROWS;
        src = Y + (size_t)r * DDIM;
        hi = Yhi + (size_t)r * DDIM; lo = Ylo + (size_t)r * DDIM;
        nrm = ny;
    }
    int t = threadIdx.x;                 // 256 threads x 4 elements
    float4 v = ((const float4*)src)[t];
    bf16x4 h, l;
    h[0] = (bf16_t)v.x; l[0] = (bf16_t)(v.x - (float)h[0]);
    h[1] = (bf16_t)v.y; l[1] = (bf16_t)(v.y - (float)h[1]);
    h[2] = (bf16_t)v.z; l[2] = (bf16_t)(v.z - (float)h[2]);
    h[3] = (bf16_t)v.w; l[3] = (bf16_t)(v.w - (float)h[3]);
    ((bf16x4*)hi)[t] = h;
    ((bf16x4*)lo)[t] = l;
    float s = v.x * v.x + v.y * v.y + v.z * v.z + v.w * v.w;
    __shared__ float red[256];
    red[t] = s;
    __syncthreads();
    for (int off = 128; off > 0; off >>= 1) {
        if (t < off) red[t] += red[t + off];
        __syncthreads();
    }
    if (t == 0) nrm[r] = red[0];
}

// ---------------------------------------------------------------- main GEMM
__global__ __launch_bounds__(256) void mmd_mfma(
    const bf16_t* __restrict__ Xhi, const bf16_t* __restrict__ Xlo,
    const bf16_t* __restrict__ Yhi, const bf16_t* __restrict__ Ylo,
    const float* __restrict__ nx, const float* __restrict__ ny,
    double* __restrict__ partials) {
    // 4 tiles: Ahi | Alo | Bhi | Blo, each BM x BK bf16 = 8 KB (32 KB total).
    // Layout: row-major, row stride BK (64 B) — contiguous, no padding
    // (required by global_load_lds wave-uniform-base + lane*16 semantics).
    __shared__ __align__(16) bf16_t lds[4 * BM * BK];
    __shared__ double red[256];

    const int b = blockIdx.x;
    const bf16_t *Ah, *Al, *Bh, *Bl;
    const float *nA, *nB;
    int tr, tc;
    double coef;
    if (b < 2 * TRI) {
        int u = (b < TRI) ? b : b - TRI;
        int r = 0;
        while (u >= NT - r) { u -= NT - r; r++; }
        tr = r; tc = r + u;
        double w = (tr == tc) ? 1.0 : 2.0;   // off-diagonal tiles count twice
        if (b < TRI) { Ah = Xhi; Al = Xlo; Bh = Xhi; Bl = Xlo; nA = nx; nB = nx;
                       coef = w / ((double)NROWS * (double)(NROWS - 1)); }
        else         { Ah = Yhi; Al = Ylo; Bh = Yhi; Bl = Ylo; nA = ny; nB = ny;
                       coef = w / ((double)MROWS * (double)(MROWS - 1)); }
    } else {
        int u = b - 2 * TRI;
        tr = u / NT; tc = u % NT;
        Ah = Xhi; Al = Xlo; Bh = Yhi; Bl = Ylo; nA = nx; nB = ny;
        coef = -2.0 / ((double)NROWS * (double)MROWS);
    }

    const int t    = threadIdx.x;
    const int wave = t >> 6;            // 0..3; waves in 2x2: wm=wave>>1, wn=wave&1
    const int lane = t & 63;
    const int wm   = wave >> 1;
    const int wn   = wave & 1;

    // staging: wave w stages tile w of {Ahi, Alo, Bhi, Blo}
    const bf16_t* mysrc;
    if      (wave == 0) mysrc = Ah + (size_t)tr * BM * DDIM;
    else if (wave == 1) mysrc = Al + (size_t)tr * BM * DDIM;
    else if (wave == 2) mysrc = Bh + (size_t)tc * BM * DDIM;
    else                mysrc = Bl + (size_t)tc * BM * DDIM;
    // per instr i: 16 rows (4 lanes/row, 16 B/lane)
    const bf16_t* gbase = mysrc + (size_t)(lane >> 2) * DDIM + (lane & 3) * 8;
    bf16_t* ldsbase = lds + wave * BM * BK;   // wave-uniform

    floatx4 acc[4][4];
    #pragma unroll
    for (int i = 0; i < 4; i++)
        #pragma unroll
        for (int j = 0; j < 4; j++) acc[i][j] = (floatx4){0.f, 0.f, 0.f, 0.f};

    const int m    = lane & 15;         // row within 16x16 subtile
    const int quad = lane >> 4;         // k-quad: k = quad*8 + j

    for (int k0 = 0; k0 < DDIM; k0 += BK) {
        __syncthreads();                 // previous compute done before overwrite
        #pragma unroll
        for (int i = 0; i < 8; i++) {
            const bf16_t* g = gbase + (size_t)(i * 16) * DDIM + k0;
            __builtin_amdgcn_global_load_lds(
                (const __attribute__((address_space(1))) void*)g,
                (__attribute__((address_space(3))) void*)(ldsbase + i * 16 * BK),
                16, 0, 0);
        }
        __syncthreads();                 // drains vmcnt before barrier

        bf16x8 ah[4], al[4], bh[4], bl[4];
        #pragma unroll
        for (int s = 0; s < 4; s++) {
            int arow = wm * 64 + s * 16 + m;
            int brow = wn * 64 + s * 16 + m;
            ah[s] = *(const bf16x8*)&lds[(0 * BM + arow) * BK + quad * 8];
            al[s] = *(const bf16x8*)&lds[(1 * BM + arow) * BK + quad * 8];
            bh[s] = *(const bf16x8*)&lds[(2 * BM + brow) * BK + quad * 8];
            bl[s] = *(const bf16x8*)&lds[(3 * BM + brow) * BK + quad * 8];
        }
        // three passes of 16 independent MFMAs (no back-to-back dependent MFMA)
        #pragma unroll
        for (int i = 0; i < 4; i++)
            #pragma unroll
            for (int j = 0; j < 4; j++)
                acc[i][j] = __builtin_amdgcn_mfma_f32_16x16x32_bf16(ah[i], bh[j], acc[i][j], 0, 0, 0);
        #pragma unroll
        for (int i = 0; i < 4; i++)
            #pragma unroll
            for (int j = 0; j < 4; j++)
                acc[i][j] = __builtin_amdgcn_mfma_f32_16x16x32_bf16(ah[i], bl[j], acc[i][j], 0, 0, 0);
        #pragma unroll
        for (int i = 0; i < 4; i++)
            #pragma unroll
            for (int j = 0; j < 4; j++)
                acc[i][j] = __builtin_amdgcn_mfma_f32_16x16x32_bf16(al[i], bh[j], acc[i][j], 0, 0, 0);
    }

    // epilogue: C/D layout col=lane&15 (B-row), row=quad*4+reg (A-row)
    float na[16], nb[4];
    #pragma unroll
    for (int i = 0; i < 4; i++) {
        #pragma unroll
        for (int r = 0; r < 4; r++)
            na[i * 4 + r] = nA[tr * BM + wm * 64 + i * 16 + quad * 4 + r];
        nb[i] = nB[tc * BM + wn * 64 + i * 16 + m];
    }
    const float inv_s2 = 1.0f / 2025.0f;
    float lsum = 0.f;
    #pragma unroll
    for (int i = 0; i < 4; i++)
        #pragma unroll
        for (int j = 0; j < 4; j++)
            #pragma unroll
            for (int r = 0; r < 4; r++) {
                float arg = (2.f * acc[i][j][r] - na[i * 4 + r] - nb[j]) * inv_s2;
                lsum += __expf(arg);
            }

    red[t] = (double)lsum;
    __syncthreads();
    for (int off = 128; off > 0; off >>= 1) {
        if (t < off) red[t] += red[t + off];
        __syncthreads();
    }
    if (t == 0) partials[b] = red[0] * coef;
}

__global__ __launch_bounds__(256) void final_reduce(const double* __restrict__ partials,
                                                    float* __restrict__ out) {
    __shared__ double red[256];
    int t = threadIdx.x;
    double s = 0.0;
    for (int i = t; i < NBLK; i += 256) s += partials[i];
    red[t] = s;
    __syncthreads();
    for (int off = 128; off > 0; off >>= 1) {
        if (t < off) red[t] += red[t + off];
        __syncthreads();
    }
    if (t == 0) {
        // analytic diagonal subtraction: 1/(n-1) + 1/(m-1)
        double mmd = red[0] - 1.0 / (double)(NROWS - 1) - 1.0 / (double)(MROWS - 1);
        out[0] = (float)mmd;
    }
}

extern "C" void kernel_launch(void* const* d_in, const int* in_sizes, int n_in,
                              void* d_out, int out_size, void* d_ws, size_t ws_size,
                              hipStream_t stream) {
    const float* X = (const float*)d_in[0];   // inputs  [4096,1024] fp32
    const float* Y = (const float*)d_in[1];   // samples [4096,1024] fp32
    float* out = (float*)d_out;

    // workspace: partials | nx | ny | Xhi | Xlo | Yhi | Ylo
    char* p = (char*)d_ws;
    double* partials = (double*)p;            p += ((size_t)NBLK * sizeof(double) + 255) & ~255ULL;
    float* nx = (float*)p;                    p += (size_t)NROWS * sizeof(float);
    float* ny = (float*)p;                    p += (size_t)MROWS * sizeof(float);
    bf16_t* Xhi = (bf16_t*)p;                 p += (size_t)NROWS * DDIM * sizeof(bf16_t);
    bf16_t* Xlo = (bf16_t*)p;                 p += (size_t)NROWS * DDIM * sizeof(bf16_t);
    bf16_t* Yhi = (bf16_t*)p;                 p += (size_t)MROWS * DDIM * sizeof(bf16_t);
    bf16_t* Ylo = (bf16_t*)p;

    convert_kernel<<<NROWS + MROWS, 256, 0, stream>>>(X, Y, Xhi, Xlo, Yhi, Ylo, nx, ny);
    mmd_mfma<<<NBLK, 256, 0, stream>>>(Xhi, Xlo, Yhi, Ylo, nx, ny, partials);
    final_reduce<<<1, 256, 0, stream>>>(partials, out);
}

// Round 3
// 165.935 us; speedup vs baseline: 5.8129x; 1.8566x over previous
//
#include <hip/hip_runtime.h>
#include <math.h>

// MMD loss, single-pass fp16 MFMA. N=M=4096, D=1024, sigma^2=2025.
// x -> xh = fp16(x) (RNE); norms computed FROM THE ROUNDED vectors so the
// kernel evaluates the exact MMD of the perturbed point sets {xh},{yh}
// (fp16 products are exact in fp32; diag dist(xh,xh)=0 exactly -> analytic
// diagonal subtraction exact). Perturbation ||delta|| ~ 4.5e-3 vs sigma=45;
// row-correlated norm components cancel between +S_xx and -2S_xy terms ->
// added error ~1e-9 vs 4.5e-8 slack (measured rounds 1-2: our fp64-summed
// result is exact; absmax 1.19e-7 is the np fp32 reference's own error).
// Cross-block accumulation in fp64 (S ~ 6.1e6, budget ~0.4).

typedef _Float16 f16_t;
typedef _Float16 f16x4 __attribute__((ext_vector_type(4)));
typedef _Float16 f16x8 __attribute__((ext_vector_type(8)));
typedef float floatx4 __attribute__((ext_vector_type(4)));

#define NROWS 4096
#define MROWS 4096
#define DDIM  1024
#define BM    128
#define BK    32                      // fp16 elements per K-step (64 B/row)
#define NT    (NROWS / BM)            // 32 tiles per dim
#define TRI   (NT * (NT + 1) / 2)     // 528 triangular tiles
#define NBLK  (2 * TRI + NT * NT)     // 2080 blocks

// ---------------------------------------------------------------- convert
// One block per row (X rows then Y rows): fp32 -> fp16 + fp32 norm of the
// ROUNDED vector (consistent geometry).
__global__ __launch_bounds__(256) void convert_kernel(
    const float* __restrict__ X, const float* __restrict__ Y,
    f16_t* __restrict__ Xh, f16_t* __restrict__ Yh,
    float* __restrict__ nx, float* __restrict__ ny) {
    int row = blockIdx.x;
    const float* src;
    f16_t* hi;
    float* nrm;
    int r;
    if (row < NROWS) {
        src = X + (size_t)row * DDIM;
        hi = Xh + (size_t)row * DDIM;
        nrm = nx; r = row;
    } else {
        r = row - NROWS;
        src = Y + (size_t)r * DDIM;
        hi = Yh + (size_t)r * DDIM;
        nrm = ny;
    }
    int t = threadIdx.x;                 // 256 threads x 4 elements
    float4 v = ((const float4*)src)[t];
    f16x4 h;
    h[0] = (f16_t)v.x; h[1] = (f16_t)v.y; h[2] = (f16_t)v.z; h[3] = (f16_t)v.w;
    ((f16x4*)hi)[t] = h;
    float h0 = (float)h[0], h1 = (float)h[1], h2 = (float)h[2], h3 = (float)h[3];
    float s = h0 * h0 + h1 * h1 + h2 * h2 + h3 * h3;
    __shared__ float red[256];
    red[t] = s;
    __syncthreads();
    for (int off = 128; off > 0; off >>= 1) {
        if (t < off) red[t] += red[t + off];
        __syncthreads();
    }
    if (t == 0) nrm[r] = red[0];
}

// ---------------------------------------------------------------- main GEMM
__global__ __launch_bounds__(256) void mmd_mfma(
    const f16_t* __restrict__ Xh, const f16_t* __restrict__ Yh,
    const float* __restrict__ nx, const float* __restrict__ ny,
    double* __restrict__ partials) {
    // 2 tiles: A | B, each BM x BK fp16 = 8 KB (16 KB total). Row-major,
    // row stride BK (64 B), contiguous (required by global_load_lds
    // wave-uniform-base + lane*16 semantics).
    __shared__ __align__(16) f16_t lds[2 * BM * BK];
    __shared__ double red[256];

    const int b = blockIdx.x;
    const f16_t *A, *B;
    const float *nA, *nB;
    int tr, tc;
    double coef;
    if (b < 2 * TRI) {
        int u = (b < TRI) ? b : b - TRI;
        int r = 0;
        while (u >= NT - r) { u -= NT - r; r++; }
        tr = r; tc = r + u;
        double w = (tr == tc) ? 1.0 : 2.0;   // off-diagonal tiles count twice
        if (b < TRI) { A = Xh; B = Xh; nA = nx; nB = nx;
                       coef = w / ((double)NROWS * (double)(NROWS - 1)); }
        else         { A = Yh; B = Yh; nA = ny; nB = ny;
                       coef = w / ((double)MROWS * (double)(MROWS - 1)); }
    } else {
        int u = b - 2 * TRI;
        tr = u / NT; tc = u % NT;
        A = Xh; B = Yh; nA = nx; nB = ny;
        coef = -2.0 / ((double)NROWS * (double)MROWS);
    }

    const int t    = threadIdx.x;
    const int wave = t >> 6;            // 0..3; waves 2x2: wm=wave>>1, wn=wave&1
    const int lane = t & 63;
    const int wm   = wave >> 1;
    const int wn   = wave & 1;

    // staging: 16 glds instrs (2 tiles x 8 row-groups of 16 rows); wave w
    // issues instrs w*4 .. w*4+3. Per instr: 64 lanes x 16 B = 16 rows.
    const f16_t* Abase = A + (size_t)tr * BM * DDIM;
    const f16_t* Bbase = B + (size_t)tc * BM * DDIM;
    const int lrow = lane >> 2;         // 0..15 within row-group
    const int lcol = (lane & 3) * 8;    // f16 elems; *2B = 16 B chunks
    const f16_t* gsrc[4];
    f16_t* gdst[4];
    #pragma unroll
    for (int i = 0; i < 4; i++) {
        int idx = wave * 4 + i;         // 0..15
        int tile = idx >> 3;            // 0=A, 1=B
        int rg   = idx & 7;             // row-group
        const f16_t* base = tile ? Bbase : Abase;
        gsrc[i] = base + (size_t)(rg * 16 + lrow) * DDIM + lcol;
        gdst[i] = lds + tile * BM * BK + (rg * 16 + lrow) * BK + lcol;
    }

    floatx4 acc[4][4];
    #pragma unroll
    for (int i = 0; i < 4; i++)
        #pragma unroll
        for (int j = 0; j < 4; j++) acc[i][j] = (floatx4){0.f, 0.f, 0.f, 0.f};

    const int m    = lane & 15;         // row within 16x16 subtile
    const int quad = lane >> 4;         // k-quad: k = quad*8 + j

    for (int k0 = 0; k0 < DDIM; k0 += BK) {
        __syncthreads();                 // previous compute done before overwrite
        #pragma unroll
        for (int i = 0; i < 4; i++) {
            __builtin_amdgcn_global_load_lds(
                (const __attribute__((address_space(1))) void*)(gsrc[i] + k0),
                (__attribute__((address_space(3))) void*)gdst[i],
                16, 0, 0);
        }
        __syncthreads();                 // drains vmcnt before barrier

        f16x8 ah[4], bh[4];
        #pragma unroll
        for (int s = 0; s < 4; s++) {
            int arow = wm * 64 + s * 16 + m;
            int brow = wn * 64 + s * 16 + m;
            ah[s] = *(const f16x8*)&lds[(0 * BM + arow) * BK + quad * 8];
            bh[s] = *(const f16x8*)&lds[(1 * BM + brow) * BK + quad * 8];
        }
        #pragma unroll
        for (int i = 0; i < 4; i++)
            #pragma unroll
            for (int j = 0; j < 4; j++)
                acc[i][j] = __builtin_amdgcn_mfma_f32_16x16x32_f16(ah[i], bh[j], acc[i][j], 0, 0, 0);
    }

    // epilogue: C/D layout col=lane&15 (B-row), row=quad*4+reg (A-row)
    float na[16], nb[4];
    #pragma unroll
    for (int i = 0; i < 4; i++) {
        #pragma unroll
        for (int r = 0; r < 4; r++)
            na[i * 4 + r] = nA[tr * BM + wm * 64 + i * 16 + quad * 4 + r];
        nb[i] = nB[tc * BM + wn * 64 + i * 16 + m];
    }
    const float inv_s2 = 1.0f / 2025.0f;
    float lsum = 0.f;
    #pragma unroll
    for (int i = 0; i < 4; i++)
        #pragma unroll
        for (int j = 0; j < 4; j++)
            #pragma unroll
            for (int r = 0; r < 4; r++) {
                float arg = (2.f * acc[i][j][r] - na[i * 4 + r] - nb[j]) * inv_s2;
                lsum += __expf(arg);
            }

    red[t] = (double)lsum;
    __syncthreads();
    for (int off = 128; off > 0; off >>= 1) {
        if (t < off) red[t] += red[t + off];
        __syncthreads();
    }
    if (t == 0) partials[b] = red[0] * coef;
}

__global__ __launch_bounds__(256) void final_reduce(const double* __restrict__ partials,
                                                    float* __restrict__ out) {
    __shared__ double red[256];
    int t = threadIdx.x;
    double s = 0.0;
    for (int i = t; i < NBLK; i += 256) s += partials[i];
    red[t] = s;
    __syncthreads();
    for (int off = 128; off > 0; off >>= 1) {
        if (t < off) red[t] += red[t + off];
        __syncthreads();
    }
    if (t == 0) {
        // analytic diagonal subtraction: 1/(n-1) + 1/(m-1)
        double mmd = red[0] - 1.0 / (double)(NROWS - 1) - 1.0 / (double)(MROWS - 1);
        out[0] = (float)mmd;
    }
}

extern "C" void kernel_launch(void* const* d_in, const int* in_sizes, int n_in,
                              void* d_out, int out_size, void* d_ws, size_t ws_size,
                              hipStream_t stream) {
    const float* X = (const float*)d_in[0];   // inputs  [4096,1024] fp32
    const float* Y = (const float*)d_in[1];   // samples [4096,1024] fp32
    float* out = (float*)d_out;

    // workspace: partials | nx | ny | Xh | Yh  (~16.7 MB)
    char* p = (char*)d_ws;
    double* partials = (double*)p;            p += ((size_t)NBLK * sizeof(double) + 255) & ~255ULL;
    float* nx = (float*)p;                    p += (size_t)NROWS * sizeof(float);
    float* ny = (float*)p;                    p += (size_t)MROWS * sizeof(float);
    f16_t* Xh = (f16_t*)p;                    p += (size_t)NROWS * DDIM * sizeof(f16_t);
    f16_t* Yh = (f16_t*)p;

    convert_kernel<<<NROWS + MROWS, 256, 0, stream>>>(X, Y, Xh, Yh, nx, ny);
    mmd_mfma<<<NBLK, 256, 0, stream>>>(Xh, Yh, nx, ny, partials);
    final_reduce<<<1, 256, 0, stream>>>(partials, out);
}